// Round 12
// baseline (342.749 us; speedup 1.0000x reference)
//
#include <hip/hip_runtime.h>
#include <stdint.h>

typedef unsigned short ushort_t;
typedef __attribute__((ext_vector_type(8))) short short8;
typedef __attribute__((ext_vector_type(8))) ushort_t u16x8;
typedef __attribute__((ext_vector_type(4))) float f32x4;

#define M_ROWS 4096
#define K_DIM  2048
#define N_GATE 8192
#define H_DIM  2048

// ---------- helpers ----------
__device__ __forceinline__ ushort_t f2bf(float f) {
    uint32_t u = __float_as_uint(f);
    uint32_t r = (u + 0x7FFFu + ((u >> 16) & 1u)) >> 16;   // RNE
    return (ushort_t)r;
}
__device__ __forceinline__ float bf2f(ushort_t b) {
    return __uint_as_float(((uint32_t)b) << 16);
}
__device__ __forceinline__ float sigf(float x) {
    return 1.0f / (1.0f + __expf(-x));
}
__device__ __forceinline__ float tanh_fast(float x) {
    float e = __expf(2.0f * x);
    return 1.0f - 2.0f / (e + 1.0f);
}

// ---------- merged prep: cvt x/h (z=0,1) + transpose W_ih/W_hh (z=2,3) ----------
// grid dim3(128, 32, 4), 256 threads.
__global__ __launch_bounds__(256) void prep_all(
    const float* __restrict__ x,   ushort_t* __restrict__ Xb,
    const float* __restrict__ h,   ushort_t* __restrict__ Hb,
    const float* __restrict__ Wih, ushort_t* __restrict__ WihT,
    const float* __restrict__ Whh, ushort_t* __restrict__ WhhT) {
    __shared__ float tile[64][65];
    const int bz = blockIdx.z;
    if (bz < 2) {
        const float* in  = bz ? h  : x;
        ushort_t*    out = bz ? Hb : Xb;
        const int i = ((blockIdx.y * 128 + blockIdx.x) * 256 + threadIdx.x) * 8;
        float4 a = *(const float4*)(in + i);
        float4 b = *(const float4*)(in + i + 4);
        u16x8 o;
        o[0] = f2bf(a.x); o[1] = f2bf(a.y); o[2] = f2bf(a.z); o[3] = f2bf(a.w);
        o[4] = f2bf(b.x); o[5] = f2bf(b.y); o[6] = f2bf(b.z); o[7] = f2bf(b.w);
        *(u16x8*)(out + i) = o;
    } else {
        const float* W  = (bz == 3) ? Whh  : Wih;
        ushort_t*    Wt = (bz == 3) ? WhhT : WihT;
        const int bn = blockIdx.x * 64;   // N
        const int bk = blockIdx.y * 64;   // K
        const int tr = threadIdx.x >> 4;          // 0..15
        const int tc = (threadIdx.x & 15) * 4;    // 0..60
#pragma unroll
        for (int i = 0; i < 64; i += 16) {
            float4 v = *(const float4*)&W[(size_t)(bk + tr + i) * N_GATE + bn + tc];
            tile[tr + i][tc]     = v.x;
            tile[tr + i][tc + 1] = v.y;
            tile[tr + i][tc + 2] = v.z;
            tile[tr + i][tc + 3] = v.w;
        }
        __syncthreads();
        const int n0 = threadIdx.x >> 3;          // 0..31
        const int k0 = (threadIdx.x & 7) * 8;     // 0..56
#pragma unroll
        for (int p = 0; p < 2; ++p) {
            const int n = n0 + p * 32;
            u16x8 o;
#pragma unroll
            for (int j = 0; j < 8; ++j)
                o[j] = f2bf(tile[k0 + j][n]);
            *(u16x8*)&Wt[(size_t)(bn + n) * K_DIM + bk + k0] = o;
        }
    }
}

// ============================================================================
// 256x256 8-phase GEMM — R8/R10-PROVEN sync structure, FROZEN PERMANENTLY.
// (R9 removed post-MM barriers -> NaN; R11 removed lgkmcnt(0) drains -> NaN.
// Mechanism: s_barrier does NOT wait for outstanding lgkm ops; the per-phase
// drain is the wave-level retire-before-release that makes cross-wave WAR
// safe. Do not touch barriers/LGKM0/VM6 placement again.)
// T2 3-bit XOR swizzle (0 conflicts), T3/T4 counted vmcnt, T5 setprio,
// identity block->XCD map, direct-store epilogue, 8/4/8/4 phase read balance.
// C[M][N] = A[M][K] @ Bt[N][K]^T, bf16 in, bf16 out. BK=64, 512 thr (2x4 waves).
// ============================================================================
#define TBK 64

__global__ __launch_bounds__(512, 2) void gemm256_8ph(
    const ushort_t* __restrict__ A0, const ushort_t* __restrict__ B0, ushort_t* __restrict__ C0,
    const ushort_t* __restrict__ A1, const ushort_t* __restrict__ B1, ushort_t* __restrict__ C1,
    int M, int N, int K) {
    extern __shared__ char smem[];   // 128 KiB: [buf(2)][A|B][half(2)][128][64] bf16, swizzled
    const ushort_t* A  = blockIdx.z ? A1 : A0;
    const ushort_t* Bt = blockIdx.z ? B1 : B0;
    ushort_t*       C  = blockIdx.z ? C1 : C0;

    const int t    = threadIdx.x;
    const int lane = t & 63, wid = t >> 6;
    const int wm   = wid >> 2, wn = wid & 3;      // 2 x 4 waves
    const int l15  = lane & 15;
    const int l4c  = (lane >> 4) * 16;            // k-byte offset component

    const int brow = blockIdx.y * 256;
    const int bcol = blockIdx.x * 256;

    // staging map: thread t -> linear LDS (row=t>>3, colbyte (t&7)*16); global source
    // column carries the inverse swizzle: elem col = ((t&7) ^ ((t>>3)&7)) * 8
    const int srow = t >> 3;                                  // 0..63
    const int scol = (((t & 7) ^ ((t >> 3) & 7)) * 8);        // pre-swizzled source col (elems)
    const ushort_t* gA = A  + (size_t)(brow + srow) * K + scol;
    const ushort_t* gB = Bt + (size_t)(bcol + srow) * K + scol;
    const int ldsw = wid * 1024;

    // fragment read offsets (bytes within a 16KB half)
    int aR[4], abit[4], bR[2], bbit[2];
#pragma unroll
    for (int fm = 0; fm < 4; ++fm) { int r = wm * 64 + fm * 16 + l15; aR[fm] = r * 128; abit[fm] = (r & 7) << 4; }
#pragma unroll
    for (int fn = 0; fn < 2; ++fn) { int r = wn * 32 + fn * 16 + l15; bR[fn] = r * 128; bbit[fn] = (r & 7) << 4; }

    f32x4 acc[8][4];
#pragma unroll
    for (int i = 0; i < 8; ++i)
#pragma unroll
        for (int j = 0; j < 4; ++j) acc[i][j] = f32x4{0.f, 0.f, 0.f, 0.f};

    short8 a[4][2], b0[2][2], b1[2][2];

#define STAGE_A(tt, h, buf) { _Pragma("unroll") for (int j = 0; j < 2; ++j) \
    __builtin_amdgcn_global_load_lds( \
        (const __attribute__((address_space(1))) void*)(gA + ((size_t)((h) * 128 + j * 64)) * K + (size_t)(tt) * TBK), \
        (__attribute__((address_space(3))) void*)(smem + (buf) * 65536 + (h) * 16384 + j * 8192 + ldsw), 16, 0, 0); }
#define STAGE_B(tt, h, buf) { _Pragma("unroll") for (int j = 0; j < 2; ++j) \
    __builtin_amdgcn_global_load_lds( \
        (const __attribute__((address_space(1))) void*)(gB + ((size_t)((h) * 128 + j * 64)) * K + (size_t)(tt) * TBK), \
        (__attribute__((address_space(3))) void*)(smem + 32768 + (buf) * 65536 + (h) * 16384 + j * 8192 + ldsw), 16, 0, 0); }
#define LDA(mh, buf) { _Pragma("unroll") for (int fm = 0; fm < 4; ++fm) _Pragma("unroll") for (int ks = 0; ks < 2; ++ks) \
    a[fm][ks] = *(const short8*)(smem + (buf) * 65536 + (mh) * 16384 + aR[fm] + ((ks * 64 + l4c) ^ abit[fm])); }
#define LDB(dst, nh, buf) { _Pragma("unroll") for (int fn = 0; fn < 2; ++fn) _Pragma("unroll") for (int ks = 0; ks < 2; ++ks) \
    dst[fn][ks] = *(const short8*)(smem + 32768 + (buf) * 65536 + (nh) * 16384 + bR[fn] + ((ks * 64 + l4c) ^ bbit[fn])); }
#define BARRIER() __builtin_amdgcn_s_barrier()
#define LGKM0()  { asm volatile("s_waitcnt lgkmcnt(0)" ::: "memory"); __builtin_amdgcn_sched_barrier(0); }
#define VM6()    asm volatile("s_waitcnt vmcnt(6)" ::: "memory")
#define MM(mh, nh, bb) { __builtin_amdgcn_s_setprio(1); \
    _Pragma("unroll") for (int ks = 0; ks < 2; ++ks) \
    _Pragma("unroll") for (int fm = 0; fm < 4; ++fm) \
    _Pragma("unroll") for (int fn = 0; fn < 2; ++fn) \
        acc[(mh) * 4 + fm][(nh) * 2 + fn] = __builtin_amdgcn_mfma_f32_16x16x32_bf16( \
            a[fm][ks], bb[fn][ks], acc[(mh) * 4 + fm][(nh) * 2 + fn], 0, 0, 0); \
    __builtin_amdgcn_s_setprio(0); }

    // ---- prologue: tile0 fully (buf0) + tile1 {Ah0,Bh0,Bh1} (buf1): 14 loads/wave ----
    STAGE_A(0, 0, 0); STAGE_B(0, 0, 0); STAGE_B(0, 1, 0); STAGE_A(0, 1, 0);
    STAGE_A(1, 0, 1); STAGE_B(1, 0, 1); STAGE_B(1, 1, 1);
    VM6();                               // oldest 8 = tile0 complete
    LDB(b0, 0, 0);                       // preload tile0 Bh0 (post-VM6: staged data guaranteed)
    BARRIER();

    const int NT = K / TBK;              // 32 (even)
    for (int tt = 0; tt < NT; tt += 2) {
        const int s2 = (tt + 2) & (NT - 1);   // wrapped prefetch (tail refetch is dead data, safe)
        const int s3 = (tt + 3) & (NT - 1);
        // ph1: reads buf0.Ah0 (b0 preloaded); stage (t+1).Ah1.  POST barrier kept:
        //      ph2 stages buf0.Ah0 (1-phase gap).
        LDA(0, 0);
        STAGE_A(tt + 1, 1, 1);
        BARRIER(); LGKM0(); MM(0, 0, b0); BARRIER();
        // ph2: reads buf0.Bh1; stage (t+2).Ah0. (readers of Bh1 retire at LGKM0 here;
        //      its restage is ph4 — ph3's barrier interposes)
        LDB(b1, 1, 0);
        STAGE_A(s2, 0, 0);
        BARRIER(); LGKM0(); MM(0, 1, b1);
        // ph3: reads buf0.Ah1; stage (t+2).Bh0. (Ah1 restaged ph5 — ph4 barrier interposes)
        LDA(1, 0);
        STAGE_B(s2, 0, 0);
        BARRIER(); LGKM0(); MM(1, 0, b0);
        // ph4: regs only; stage (t+2).Bh1; VM6; preload buf1.Bh0 (retired by VM6)
        STAGE_B(s2, 1, 0);
        VM6();
        LDB(b0, 0, 1);
        BARRIER(); LGKM0(); MM(1, 1, b1);
        // ph5: reads buf1.Ah0; stage (t+2).Ah1.  POST barrier kept:
        //      ph6 stages buf1.Ah0 (1-phase gap).
        LDA(0, 1);
        STAGE_A(s2, 1, 0);
        BARRIER(); LGKM0(); MM(0, 0, b0); BARRIER();
        // ph6: reads buf1.Bh1; stage (t+3).Ah0. (Bh1 restaged ph8 — ph7 barrier interposes)
        LDB(b1, 1, 1);
        STAGE_A(s3, 0, 1);
        BARRIER(); LGKM0(); MM(0, 1, b1);
        // ph7: reads buf1.Ah1; stage (t+3).Bh0. (Ah1 restaged next ph1 — ph8 barrier interposes)
        LDA(1, 1);
        STAGE_B(s3, 0, 1);
        BARRIER(); LGKM0(); MM(1, 0, b0);
        // ph8: stage (t+3).Bh1; VM6; preload buf0.Bh0=(t+2).Bh0 (retired by VM6)
        STAGE_B(s3, 1, 1);
        VM6();
        LDB(b0, 0, 0);
        BARRIER(); LGKM0(); MM(1, 1, b1);
    }

    // ---- epilogue: direct stores, C/D frag layout col=lane&15, row=(lane>>4)*4+r ----
    // (in-flight wrapped prefetches still write smem; nothing reads smem — harmless)
#pragma unroll
    for (int i = 0; i < 8; ++i) {
        const int mh = i >> 2, fm = i & 3;
        const int row0 = brow + mh * 128 + wm * 64 + fm * 16 + (lane >> 4) * 4;
#pragma unroll
        for (int jn = 0; jn < 4; ++jn) {
            const int nh = jn >> 1, fn = jn & 1;
            const int col = bcol + nh * 128 + wn * 32 + fn * 16 + l15;
#pragma unroll
            for (int r = 0; r < 4; ++r)
                C[(size_t)(row0 + r) * N + col] = f2bf(acc[i][jn][r]);
        }
    }
#undef STAGE_A
#undef STAGE_B
#undef LDA
#undef LDB
#undef BARRIER
#undef LGKM0
#undef VM6
#undef MM
}

// ---------- block reduction of two sums over 256 threads ----------
__device__ __forceinline__ void block_reduce2(float& a, float& b, float* sred, int t) {
#pragma unroll
    for (int o = 32; o; o >>= 1) {
        a += __shfl_down(a, o);
        b += __shfl_down(b, o);
    }
    __syncthreads();
    if ((t & 63) == 0) { int w = t >> 6; sred[w] = a; sred[4 + w] = b; }
    __syncthreads();
    a = sred[0] + sred[1] + sred[2] + sred[3];
    b = sred[4] + sred[5] + sred[6] + sred[7];
}

// ---------- fused LN(x-gates) + gate nonlinearities + cell LN + h LN ----------
// One block (256 threads) per batch row. REGISTER-RESIDENT (R12): phase-1's
// load map (it*2048 + t*8) is exactly phase-2's per-gate map (gate*2048 + t*8),
// so thread t keeps its 32 xW values in xg[4][8] registers — the 32 KB sgx LDS
// staging (8192 writes + 8192 reads/block) is deleted. All xg indices are
// compile-time (rule #20: no scratch).
__global__ __launch_bounds__(256) void fuse_ln_lstm(
    const ushort_t* __restrict__ xW, const ushort_t* __restrict__ hW,
    const float* __restrict__ c_prev,
    const float* __restrict__ b_ih, const float* __restrict__ b_hh,
    const float* __restrict__ g_x, const float* __restrict__ beta_x,
    const float* __restrict__ g_c, const float* __restrict__ beta_c,
    const float* __restrict__ g_h, const float* __restrict__ beta_h,
    float* __restrict__ h_out, float* __restrict__ c_out) {

    __shared__ float sred[8];

    const int b = blockIdx.x;
    const int t = threadIdx.x;
    const ushort_t* xwr = xW + (size_t)b * N_GATE;
    const ushort_t* hwr = hW + (size_t)b * N_GATE;
    const float*    cpr = c_prev + (size_t)b * H_DIM;

    // ---- phase 1: load xW (+bias) into registers, LN stats over 8192 ----
    float xg[4][8];
    float s = 0.f, q = 0.f;
#pragma unroll
    for (int it = 0; it < 4; ++it) {
        const int idx = it * 2048 + t * 8;
        short8 v = *(const short8*)&xwr[idx];
        float bi[8];
        *(float4*)&bi[0] = *(const float4*)&b_ih[idx];
        *(float4*)&bi[4] = *(const float4*)&b_ih[idx + 4];
#pragma unroll
        for (int j = 0; j < 8; ++j) {
            float f = bf2f((ushort_t)v[j]) + bi[j];
            xg[it][j] = f;
            s += f; q += f * f;
        }
    }
    block_reduce2(s, q, sred, t);
    const float inv_g = 1.0f / (float)N_GATE;
    float mu   = s * inv_g;
    float rstd = rsqrtf(q * inv_g - mu * mu + 1e-5f);

    // ---- phase 2: gates (8 consecutive j per thread per quarter), cell; stats ----
    const int j0 = t * 8;
    float gi[8], gf[8], gg[8], go[8];
#define GATE(dst, it) { \
    const int jj = j0 + (it) * 2048; \
    short8 hv = *(const short8*)&hwr[jj]; \
    float bh[8], gx[8], bx[8]; \
    *(float4*)&bh[0] = *(const float4*)&b_hh[jj];   *(float4*)&bh[4] = *(const float4*)&b_hh[jj + 4]; \
    *(float4*)&gx[0] = *(const float4*)&g_x[jj];    *(float4*)&gx[4] = *(const float4*)&g_x[jj + 4]; \
    *(float4*)&bx[0] = *(const float4*)&beta_x[jj]; *(float4*)&bx[4] = *(const float4*)&beta_x[jj + 4]; \
    _Pragma("unroll") for (int u = 0; u < 8; ++u) \
        dst[u] = (xg[it][u] - mu) * rstd * gx[u] + bx[u] + bf2f((ushort_t)hv[u]) + bh[u]; }
    GATE(gi, 0); GATE(gf, 1); GATE(gg, 2); GATE(go, 3);
#undef GATE
    float cp[8];
    *(float4*)&cp[0] = *(const float4*)&cpr[j0];
    *(float4*)&cp[4] = *(const float4*)&cpr[j0 + 4];
    float cell[8], ot[8];
    float cs = 0.f, cq = 0.f;
#pragma unroll
    for (int u = 0; u < 8; ++u) {
        float i_t = sigf(gi[u]);
        float f_t = sigf(gf[u]);
        float g_t = tanh_fast(gg[u]);
        ot[u]     = sigf(go[u]);
        cell[u]   = f_t * cp[u] + i_t * g_t;
        cs += cell[u]; cq += cell[u] * cell[u];
    }
    block_reduce2(cs, cq, sred, t);
    const float inv_h = 1.0f / (float)H_DIM;
    float muc   = cs * inv_h;
    float rstdc = rsqrtf(cq * inv_h - muc * muc + 1e-5f);

    // ---- phase 3: c_t out, h pre-LN stats (hp in regs) ----
    float gc[8], bc[8];
    *(float4*)&gc[0] = *(const float4*)&g_c[j0];    *(float4*)&gc[4] = *(const float4*)&g_c[j0 + 4];
    *(float4*)&bc[0] = *(const float4*)&beta_c[j0]; *(float4*)&bc[4] = *(const float4*)&beta_c[j0 + 4];
    float ct[8], hp[8];
    float hs = 0.f, hq = 0.f;
#pragma unroll
    for (int u = 0; u < 8; ++u) {
        ct[u] = (cell[u] - muc) * rstdc * gc[u] + bc[u];
        hp[u] = ot[u] * tanh_fast(ct[u]);
        hs += hp[u]; hq += hp[u] * hp[u];
    }
    float* cout = c_out + (size_t)b * H_DIM + j0;
    *(float4*)&cout[0] = *(const float4*)&ct[0];
    *(float4*)&cout[4] = *(const float4*)&ct[4];
    block_reduce2(hs, hq, sred, t);
    float muh   = hs * inv_h;
    float rstdh = rsqrtf(hq * inv_h - muh * muh + 1e-5f);

    // ---- phase 4: h_t out ----
    float gh[8], bh2[8];
    *(float4*)&gh[0]  = *(const float4*)&g_h[j0];    *(float4*)&gh[4]  = *(const float4*)&g_h[j0 + 4];
    *(float4*)&bh2[0] = *(const float4*)&beta_h[j0]; *(float4*)&bh2[4] = *(const float4*)&beta_h[j0 + 4];
    float ho[8];
#pragma unroll
    for (int u = 0; u < 8; ++u)
        ho[u] = (hp[u] - muh) * rstdh * gh[u] + bh2[u];
    float* hout = h_out + (size_t)b * H_DIM + j0;
    *(float4*)&hout[0] = *(const float4*)&ho[0];
    *(float4*)&hout[4] = *(const float4*)&ho[4];
}

// ---------- launch ----------
extern "C" void kernel_launch(void* const* d_in, const int* in_sizes, int n_in,
                              void* d_out, int out_size, void* d_ws, size_t ws_size,
                              hipStream_t stream) {
    const float* x      = (const float*)d_in[0];
    const float* h_prev = (const float*)d_in[1];
    const float* c_prev = (const float*)d_in[2];
    const float* W_ih   = (const float*)d_in[3];
    const float* W_hh   = (const float*)d_in[4];
    const float* b_ih   = (const float*)d_in[5];
    const float* b_hh   = (const float*)d_in[6];
    const float* g_x    = (const float*)d_in[7];
    const float* beta_x = (const float*)d_in[8];
    const float* g_c    = (const float*)d_in[9];
    const float* beta_c = (const float*)d_in[10];
    const float* g_h    = (const float*)d_in[11];
    const float* beta_h = (const float*)d_in[12];

    const int M = M_ROWS, K = K_DIM, N = N_GATE;

    ushort_t* Xb   = (ushort_t*)d_ws;
    ushort_t* Hb   = Xb   + (size_t)M * K;
    ushort_t* WihT = Hb   + (size_t)M * K;
    ushort_t* WhhT = WihT + (size_t)N * K;
    ushort_t* xWb  = WhhT + (size_t)N * K;
    ushort_t* hWb  = xWb  + (size_t)M * N;

    prep_all<<<dim3(128, 32, 4), 256, 0, stream>>>(
        x, Xb, h_prev, Hb, W_ih, WihT, W_hh, WhhT);

    static int lds_attr_set = 0;
    if (!lds_attr_set) {
        (void)hipFuncSetAttribute(reinterpret_cast<const void*>(&gemm256_8ph),
                                  hipFuncAttributeMaxDynamicSharedMemorySize, 131072);
        lds_attr_set = 1;
    }
    gemm256_8ph<<<dim3(N / 256, M / 256, 2), 512, 131072, stream>>>(
        Xb, WihT, xWb, Hb, WhhT, hWb, M, N, K);

    float* h_out = (float*)d_out;
    float* c_out = h_out + (size_t)M * H_DIM;
    fuse_ln_lstm<<<M, 256, 0, stream>>>(xWb, hWb, c_prev, b_ih, b_hh,
                                        g_x, beta_x, g_c, beta_c, g_h, beta_h,
                                        h_out, c_out);
}

// Round 14
// 340.695 us; speedup vs baseline: 1.0060x; 1.0060x over previous
//
#include <hip/hip_runtime.h>
#include <stdint.h>

typedef unsigned short ushort_t;
typedef __attribute__((ext_vector_type(8))) short short8;
typedef __attribute__((ext_vector_type(8))) ushort_t u16x8;
typedef __attribute__((ext_vector_type(4))) float f32x4;

#define M_ROWS 4096
#define K_DIM  2048
#define N_GATE 8192
#define H_DIM  2048

// ---------- helpers ----------
__device__ __forceinline__ ushort_t f2bf(float f) {
    uint32_t u = __float_as_uint(f);
    uint32_t r = (u + 0x7FFFu + ((u >> 16) & 1u)) >> 16;   // RNE
    return (ushort_t)r;
}
__device__ __forceinline__ float bf2f(ushort_t b) {
    return __uint_as_float(((uint32_t)b) << 16);
}
__device__ __forceinline__ float sigf(float x) {
    return 1.0f / (1.0f + __expf(-x));
}
__device__ __forceinline__ float tanh_fast(float x) {
    float e = __expf(2.0f * x);
    return 1.0f - 2.0f / (e + 1.0f);
}

// ---------- merged prep: cvt x/h (z=0,1) + transpose W_ih/W_hh (z=2,3) ----------
// grid dim3(128, 32, 4), 256 threads.
__global__ __launch_bounds__(256) void prep_all(
    const float* __restrict__ x,   ushort_t* __restrict__ Xb,
    const float* __restrict__ h,   ushort_t* __restrict__ Hb,
    const float* __restrict__ Wih, ushort_t* __restrict__ WihT,
    const float* __restrict__ Whh, ushort_t* __restrict__ WhhT) {
    __shared__ float tile[64][65];
    const int bz = blockIdx.z;
    if (bz < 2) {
        const float* in  = bz ? h  : x;
        ushort_t*    out = bz ? Hb : Xb;
        const int i = ((blockIdx.y * 128 + blockIdx.x) * 256 + threadIdx.x) * 8;
        float4 a = *(const float4*)(in + i);
        float4 b = *(const float4*)(in + i + 4);
        u16x8 o;
        o[0] = f2bf(a.x); o[1] = f2bf(a.y); o[2] = f2bf(a.z); o[3] = f2bf(a.w);
        o[4] = f2bf(b.x); o[5] = f2bf(b.y); o[6] = f2bf(b.z); o[7] = f2bf(b.w);
        *(u16x8*)(out + i) = o;
    } else {
        const float* W  = (bz == 3) ? Whh  : Wih;
        ushort_t*    Wt = (bz == 3) ? WhhT : WihT;
        const int bn = blockIdx.x * 64;   // N
        const int bk = blockIdx.y * 64;   // K
        const int tr = threadIdx.x >> 4;          // 0..15
        const int tc = (threadIdx.x & 15) * 4;    // 0..60
#pragma unroll
        for (int i = 0; i < 64; i += 16) {
            float4 v = *(const float4*)&W[(size_t)(bk + tr + i) * N_GATE + bn + tc];
            tile[tr + i][tc]     = v.x;
            tile[tr + i][tc + 1] = v.y;
            tile[tr + i][tc + 2] = v.z;
            tile[tr + i][tc + 3] = v.w;
        }
        __syncthreads();
        const int n0 = threadIdx.x >> 3;          // 0..31
        const int k0 = (threadIdx.x & 7) * 8;     // 0..56
#pragma unroll
        for (int p = 0; p < 2; ++p) {
            const int n = n0 + p * 32;
            u16x8 o;
#pragma unroll
            for (int j = 0; j < 8; ++j)
                o[j] = f2bf(tile[k0 + j][n]);
            *(u16x8*)&Wt[(size_t)(bn + n) * K_DIM + bk + k0] = o;
        }
    }
}

// ============================================================================
// 256x256 8-phase GEMM — R8/R10-PROVEN sync structure, FROZEN PERMANENTLY.
// Session post-mortem of 3 NaN'd neighbors (R9: fewer barriers, R11: no
// lgkm drains, R13: peeled tail with provably-correct source-level ledger):
// the emitted placement of global_load_lds relative to barriers is not
// reliably source-controlled (its LDS-write side effect appears incompletely
// modeled), so ANY perturbation of this loop's shape re-rolls scheduling.
// This exact form passed 3x at GEMM=231us / MfmaUtil 55% / 0 bank conflicts.
// T2 3-bit XOR swizzle, T3/T4 counted vmcnt, T5 setprio, identity block->XCD
// map (col==k mod 8 keeps B-panels L2-resident), direct-store epilogue,
// 8/4/8/4 phase ds_read balance, 10 barriers/iter.
// C[M][N] = A[M][K] @ Bt[N][K]^T, bf16 in, bf16 out. BK=64, 512 thr (2x4 waves).
// ============================================================================
#define TBK 64

__global__ __launch_bounds__(512, 2) void gemm256_8ph(
    const ushort_t* __restrict__ A0, const ushort_t* __restrict__ B0, ushort_t* __restrict__ C0,
    const ushort_t* __restrict__ A1, const ushort_t* __restrict__ B1, ushort_t* __restrict__ C1,
    int M, int N, int K) {
    extern __shared__ char smem[];   // 128 KiB: [buf(2)][A|B][half(2)][128][64] bf16, swizzled
    const ushort_t* A  = blockIdx.z ? A1 : A0;
    const ushort_t* Bt = blockIdx.z ? B1 : B0;
    ushort_t*       C  = blockIdx.z ? C1 : C0;

    const int t    = threadIdx.x;
    const int lane = t & 63, wid = t >> 6;
    const int wm   = wid >> 2, wn = wid & 3;      // 2 x 4 waves
    const int l15  = lane & 15;
    const int l4c  = (lane >> 4) * 16;            // k-byte offset component

    const int brow = blockIdx.y * 256;
    const int bcol = blockIdx.x * 256;

    // staging map: thread t -> linear LDS (row=t>>3, colbyte (t&7)*16); global source
    // column carries the inverse swizzle: elem col = ((t&7) ^ ((t>>3)&7)) * 8
    const int srow = t >> 3;                                  // 0..63
    const int scol = (((t & 7) ^ ((t >> 3) & 7)) * 8);        // pre-swizzled source col (elems)
    const ushort_t* gA = A  + (size_t)(brow + srow) * K + scol;
    const ushort_t* gB = Bt + (size_t)(bcol + srow) * K + scol;
    const int ldsw = wid * 1024;

    // fragment read offsets (bytes within a 16KB half)
    int aR[4], abit[4], bR[2], bbit[2];
#pragma unroll
    for (int fm = 0; fm < 4; ++fm) { int r = wm * 64 + fm * 16 + l15; aR[fm] = r * 128; abit[fm] = (r & 7) << 4; }
#pragma unroll
    for (int fn = 0; fn < 2; ++fn) { int r = wn * 32 + fn * 16 + l15; bR[fn] = r * 128; bbit[fn] = (r & 7) << 4; }

    f32x4 acc[8][4];
#pragma unroll
    for (int i = 0; i < 8; ++i)
#pragma unroll
        for (int j = 0; j < 4; ++j) acc[i][j] = f32x4{0.f, 0.f, 0.f, 0.f};

    short8 a[4][2], b0[2][2], b1[2][2];

#define STAGE_A(tt, h, buf) { _Pragma("unroll") for (int j = 0; j < 2; ++j) \
    __builtin_amdgcn_global_load_lds( \
        (const __attribute__((address_space(1))) void*)(gA + ((size_t)((h) * 128 + j * 64)) * K + (size_t)(tt) * TBK), \
        (__attribute__((address_space(3))) void*)(smem + (buf) * 65536 + (h) * 16384 + j * 8192 + ldsw), 16, 0, 0); }
#define STAGE_B(tt, h, buf) { _Pragma("unroll") for (int j = 0; j < 2; ++j) \
    __builtin_amdgcn_global_load_lds( \
        (const __attribute__((address_space(1))) void*)(gB + ((size_t)((h) * 128 + j * 64)) * K + (size_t)(tt) * TBK), \
        (__attribute__((address_space(3))) void*)(smem + 32768 + (buf) * 65536 + (h) * 16384 + j * 8192 + ldsw), 16, 0, 0); }
#define LDA(mh, buf) { _Pragma("unroll") for (int fm = 0; fm < 4; ++fm) _Pragma("unroll") for (int ks = 0; ks < 2; ++ks) \
    a[fm][ks] = *(const short8*)(smem + (buf) * 65536 + (mh) * 16384 + aR[fm] + ((ks * 64 + l4c) ^ abit[fm])); }
#define LDB(dst, nh, buf) { _Pragma("unroll") for (int fn = 0; fn < 2; ++fn) _Pragma("unroll") for (int ks = 0; ks < 2; ++ks) \
    dst[fn][ks] = *(const short8*)(smem + 32768 + (buf) * 65536 + (nh) * 16384 + bR[fn] + ((ks * 64 + l4c) ^ bbit[fn])); }
#define BARRIER() __builtin_amdgcn_s_barrier()
#define LGKM0()  { asm volatile("s_waitcnt lgkmcnt(0)" ::: "memory"); __builtin_amdgcn_sched_barrier(0); }
#define VM6()    asm volatile("s_waitcnt vmcnt(6)" ::: "memory")
#define MM(mh, nh, bb) { __builtin_amdgcn_s_setprio(1); \
    _Pragma("unroll") for (int ks = 0; ks < 2; ++ks) \
    _Pragma("unroll") for (int fm = 0; fm < 4; ++fm) \
    _Pragma("unroll") for (int fn = 0; fn < 2; ++fn) \
        acc[(mh) * 4 + fm][(nh) * 2 + fn] = __builtin_amdgcn_mfma_f32_16x16x32_bf16( \
            a[fm][ks], bb[fn][ks], acc[(mh) * 4 + fm][(nh) * 2 + fn], 0, 0, 0); \
    __builtin_amdgcn_s_setprio(0); }

    // ---- prologue: tile0 fully (buf0) + tile1 {Ah0,Bh0,Bh1} (buf1): 14 loads/wave ----
    STAGE_A(0, 0, 0); STAGE_B(0, 0, 0); STAGE_B(0, 1, 0); STAGE_A(0, 1, 0);
    STAGE_A(1, 0, 1); STAGE_B(1, 0, 1); STAGE_B(1, 1, 1);
    VM6();                               // oldest 8 = tile0 complete
    LDB(b0, 0, 0);                       // preload tile0 Bh0 (post-VM6: staged data guaranteed)
    BARRIER();

    const int NT = K / TBK;              // 32 (even)
    for (int tt = 0; tt < NT; tt += 2) {
        const int s2 = (tt + 2) & (NT - 1);   // wrapped prefetch (tail refetch is dead data, safe)
        const int s3 = (tt + 3) & (NT - 1);
        // ph1: reads buf0.Ah0 (b0 preloaded); stage (t+1).Ah1.  POST barrier kept:
        //      ph2 stages buf0.Ah0 (1-phase gap).
        LDA(0, 0);
        STAGE_A(tt + 1, 1, 1);
        BARRIER(); LGKM0(); MM(0, 0, b0); BARRIER();
        // ph2: reads buf0.Bh1; stage (t+2).Ah0. (readers of Bh1 retire at LGKM0 here;
        //      its restage is ph4 — ph3's barrier interposes)
        LDB(b1, 1, 0);
        STAGE_A(s2, 0, 0);
        BARRIER(); LGKM0(); MM(0, 1, b1);
        // ph3: reads buf0.Ah1; stage (t+2).Bh0. (Ah1 restaged ph5 — ph4 barrier interposes)
        LDA(1, 0);
        STAGE_B(s2, 0, 0);
        BARRIER(); LGKM0(); MM(1, 0, b0);
        // ph4: regs only; stage (t+2).Bh1; VM6; preload buf1.Bh0 (retired by VM6)
        STAGE_B(s2, 1, 0);
        VM6();
        LDB(b0, 0, 1);
        BARRIER(); LGKM0(); MM(1, 1, b1);
        // ph5: reads buf1.Ah0; stage (t+2).Ah1.  POST barrier kept:
        //      ph6 stages buf1.Ah0 (1-phase gap).
        LDA(0, 1);
        STAGE_A(s2, 1, 0);
        BARRIER(); LGKM0(); MM(0, 0, b0); BARRIER();
        // ph6: reads buf1.Bh1; stage (t+3).Ah0. (Bh1 restaged ph8 — ph7 barrier interposes)
        LDB(b1, 1, 1);
        STAGE_A(s3, 0, 1);
        BARRIER(); LGKM0(); MM(0, 1, b1);
        // ph7: reads buf1.Ah1; stage (t+3).Bh0. (Ah1 restaged next ph1 — ph8 barrier interposes)
        LDA(1, 1);
        STAGE_B(s3, 0, 1);
        BARRIER(); LGKM0(); MM(1, 0, b0);
        // ph8: stage (t+3).Bh1; VM6; preload buf0.Bh0=(t+2).Bh0 (retired by VM6)
        STAGE_B(s3, 1, 1);
        VM6();
        LDB(b0, 0, 0);
        BARRIER(); LGKM0(); MM(1, 1, b1);
    }

    // ---- epilogue: direct stores, C/D frag layout col=lane&15, row=(lane>>4)*4+r ----
    // (in-flight wrapped prefetches still write smem; nothing reads smem — harmless)
#pragma unroll
    for (int i = 0; i < 8; ++i) {
        const int mh = i >> 2, fm = i & 3;
        const int row0 = brow + mh * 128 + wm * 64 + fm * 16 + (lane >> 4) * 4;
#pragma unroll
        for (int jn = 0; jn < 4; ++jn) {
            const int nh = jn >> 1, fn = jn & 1;
            const int col = bcol + nh * 128 + wn * 32 + fn * 16 + l15;
#pragma unroll
            for (int r = 0; r < 4; ++r)
                C[(size_t)(row0 + r) * N + col] = f2bf(acc[i][jn][r]);
        }
    }
#undef STAGE_A
#undef STAGE_B
#undef LDA
#undef LDB
#undef BARRIER
#undef LGKM0
#undef VM6
#undef MM
}

// ---------- block reduction of two sums over 256 threads ----------
__device__ __forceinline__ void block_reduce2(float& a, float& b, float* sred, int t) {
#pragma unroll
    for (int o = 32; o; o >>= 1) {
        a += __shfl_down(a, o);
        b += __shfl_down(b, o);
    }
    __syncthreads();
    if ((t & 63) == 0) { int w = t >> 6; sred[w] = a; sred[4 + w] = b; }
    __syncthreads();
    a = sred[0] + sred[1] + sred[2] + sred[3];
    b = sred[4] + sred[5] + sred[6] + sred[7];
}

// ---------- fused LN(x-gates) + gate nonlinearities + cell LN + h LN ----------
// one block (256 threads) per batch row; 8 consecutive j per thread; cell/o_t/hp in regs
__global__ __launch_bounds__(256) void fuse_ln_lstm(
    const ushort_t* __restrict__ xW, const ushort_t* __restrict__ hW,
    const float* __restrict__ c_prev,
    const float* __restrict__ b_ih, const float* __restrict__ b_hh,
    const float* __restrict__ g_x, const float* __restrict__ beta_x,
    const float* __restrict__ g_c, const float* __restrict__ beta_c,
    const float* __restrict__ g_h, const float* __restrict__ beta_h,
    float* __restrict__ h_out, float* __restrict__ c_out) {

    __shared__ float sgx[N_GATE];     // 32 KB
    __shared__ float sred[8];

    const int b = blockIdx.x;
    const int t = threadIdx.x;
    const ushort_t* xwr = xW + (size_t)b * N_GATE;
    const ushort_t* hwr = hW + (size_t)b * N_GATE;
    const float*    cpr = c_prev + (size_t)b * H_DIM;

    // ---- phase 1: xW row -> LDS (+bias), LN stats over 8192 ----
    float s = 0.f, q = 0.f;
#pragma unroll
    for (int it = 0; it < 4; ++it) {
        int idx = it * 2048 + t * 8;
        short8 v = *(const short8*)&xwr[idx];
        float bi[8];
        *(float4*)&bi[0] = *(const float4*)&b_ih[idx];
        *(float4*)&bi[4] = *(const float4*)&b_ih[idx + 4];
#pragma unroll
        for (int j = 0; j < 8; ++j) {
            float f = bf2f((ushort_t)v[j]) + bi[j];
            sgx[idx + j] = f;
            s += f; q += f * f;
        }
    }
    block_reduce2(s, q, sred, t);
    const float inv_g = 1.0f / (float)N_GATE;
    float mu   = s * inv_g;
    float rstd = rsqrtf(q * inv_g - mu * mu + 1e-5f);

    // ---- phase 2: gates (8 consecutive j per thread per quarter), cell; stats ----
    const int j0 = t * 8;
    float gi[8], gf[8], gg[8], go[8];
#define GATE(dst, off) { \
    const int jj = j0 + (off); \
    short8 hv = *(const short8*)&hwr[jj]; \
    float bh[8], gx[8], bx[8]; \
    *(float4*)&bh[0] = *(const float4*)&b_hh[jj];   *(float4*)&bh[4] = *(const float4*)&b_hh[jj + 4]; \
    *(float4*)&gx[0] = *(const float4*)&g_x[jj];    *(float4*)&gx[4] = *(const float4*)&g_x[jj + 4]; \
    *(float4*)&bx[0] = *(const float4*)&beta_x[jj]; *(float4*)&bx[4] = *(const float4*)&beta_x[jj + 4]; \
    _Pragma("unroll") for (int u = 0; u < 8; ++u) \
        dst[u] = (sgx[jj + u] - mu) * rstd * gx[u] + bx[u] + bf2f((ushort_t)hv[u]) + bh[u]; }
    GATE(gi, 0); GATE(gf, 2048); GATE(gg, 4096); GATE(go, 6144);
#undef GATE
    float cp[8];
    *(float4*)&cp[0] = *(const float4*)&cpr[j0];
    *(float4*)&cp[4] = *(const float4*)&cpr[j0 + 4];
    float cell[8], ot[8];
    float cs = 0.f, cq = 0.f;
#pragma unroll
    for (int u = 0; u < 8; ++u) {
        float i_t = sigf(gi[u]);
        float f_t = sigf(gf[u]);
        float g_t = tanh_fast(gg[u]);
        ot[u]     = sigf(go[u]);
        cell[u]   = f_t * cp[u] + i_t * g_t;
        cs += cell[u]; cq += cell[u] * cell[u];
    }
    block_reduce2(cs, cq, sred, t);
    const float inv_h = 1.0f / (float)H_DIM;
    float muc   = cs * inv_h;
    float rstdc = rsqrtf(cq * inv_h - muc * muc + 1e-5f);

    // ---- phase 3: c_t out, h pre-LN stats (hp in regs) ----
    float gc[8], bc[8];
    *(float4*)&gc[0] = *(const float4*)&g_c[j0];    *(float4*)&gc[4] = *(const float4*)&g_c[j0 + 4];
    *(float4*)&bc[0] = *(const float4*)&beta_c[j0]; *(float4*)&bc[4] = *(const float4*)&beta_c[j0 + 4];
    float ct[8], hp[8];
    float hs = 0.f, hq = 0.f;
#pragma unroll
    for (int u = 0; u < 8; ++u) {
        ct[u] = (cell[u] - muc) * rstdc * gc[u] + bc[u];
        hp[u] = ot[u] * tanh_fast(ct[u]);
        hs += hp[u]; hq += hp[u] * hp[u];
    }
    float* cout = c_out + (size_t)b * H_DIM + j0;
    *(float4*)&cout[0] = *(const float4*)&ct[0];
    *(float4*)&cout[4] = *(const float4*)&ct[4];
    block_reduce2(hs, hq, sred, t);
    float muh   = hs * inv_h;
    float rstdh = rsqrtf(hq * inv_h - muh * muh + 1e-5f);

    // ---- phase 4: h_t out ----
    float gh[8], bh2[8];
    *(float4*)&gh[0]  = *(const float4*)&g_h[j0];    *(float4*)&gh[4]  = *(const float4*)&g_h[j0 + 4];
    *(float4*)&bh2[0] = *(const float4*)&beta_h[j0]; *(float4*)&bh2[4] = *(const float4*)&beta_h[j0 + 4];
    float ho[8];
#pragma unroll
    for (int u = 0; u < 8; ++u)
        ho[u] = (hp[u] - muh) * rstdh * gh[u] + bh2[u];
    float* hout = h_out + (size_t)b * H_DIM + j0;
    *(float4*)&hout[0] = *(const float4*)&ho[0];
    *(float4*)&hout[4] = *(const float4*)&ho[4];
}

// ---------- launch ----------
extern "C" void kernel_launch(void* const* d_in, const int* in_sizes, int n_in,
                              void* d_out, int out_size, void* d_ws, size_t ws_size,
                              hipStream_t stream) {
    const float* x      = (const float*)d_in[0];
    const float* h_prev = (const float*)d_in[1];
    const float* c_prev = (const float*)d_in[2];
    const float* W_ih   = (const float*)d_in[3];
    const float* W_hh   = (const float*)d_in[4];
    const float* b_ih   = (const float*)d_in[5];
    const float* b_hh   = (const float*)d_in[6];
    const float* g_x    = (const float*)d_in[7];
    const float* beta_x = (const float*)d_in[8];
    const float* g_c    = (const float*)d_in[9];
    const float* beta_c = (const float*)d_in[10];
    const float* g_h    = (const float*)d_in[11];
    const float* beta_h = (const float*)d_in[12];

    const int M = M_ROWS, K = K_DIM, N = N_GATE;

    ushort_t* Xb   = (ushort_t*)d_ws;
    ushort_t* Hb   = Xb   + (size_t)M * K;
    ushort_t* WihT = Hb   + (size_t)M * K;
    ushort_t* WhhT = WihT + (size_t)N * K;
    ushort_t* xWb  = WhhT + (size_t)N * K;
    ushort_t* hWb  = xWb  + (size_t)M * N;

    prep_all<<<dim3(128, 32, 4), 256, 0, stream>>>(
        x, Xb, h_prev, Hb, W_ih, WihT, W_hh, WhhT);

    static int lds_attr_set = 0;
    if (!lds_attr_set) {
        (void)hipFuncSetAttribute(reinterpret_cast<const void*>(&gemm256_8ph),
                                  hipFuncAttributeMaxDynamicSharedMemorySize, 131072);
        lds_attr_set = 1;
    }
    gemm256_8ph<<<dim3(N / 256, M / 256, 2), 512, 131072, stream>>>(
        Xb, WihT, xWb, Hb, WhhT, hWb, M, N, K);

    float* h_out = (float*)d_out;
    float* c_out = h_out + (size_t)M * H_DIM;
    fuse_ln_lstm<<<M, 256, 0, stream>>>(xWb, hWb, c_prev, b_ih, b_hh,
                                        g_x, beta_x, g_c, beta_c, g_h, beta_h,
                                        h_out, c_out);
}